// Round 4
// baseline (276.107 us; speedup 1.0000x reference)
//
#include <hip/hip_runtime.h>
#include <stdint.h>

typedef __attribute__((ext_vector_type(4))) float f32x4;
typedef __attribute__((ext_vector_type(8))) short short8;

#define HEADS 16
#define TT 2048

// Sanitize raw input values: NaN/Inf/garbage-huge -> 0. Insurance against a
// dtype misread; in the correct-dtype world this is a no-op on real data.
__device__ __forceinline__ float san(float v) {
  return (v == v && v > -1e30f && v < 1e30f) ? v : 0.f;
}
__device__ __forceinline__ float b2f(unsigned short u) {
  return __builtin_bit_cast(float, (uint32_t)u << 16);
}
__device__ __forceinline__ unsigned short f2bf(float f) {
  uint32_t u = __builtin_bit_cast(uint32_t, f);
  u += 0x7fffu + ((u >> 16) & 1u);
  return (unsigned short)(u >> 16);
}
__device__ __forceinline__ uint32_t pk2(float a, float b) {
  return (uint32_t)f2bf(a) | ((uint32_t)f2bf(b) << 16);
}

// p[h][i] = sum_d Wk[i,h,d] * q[h,d]   (fold q into kv K-half; fp32)
__global__ void prep_p(const float* __restrict__ kv, const float* __restrict__ q,
                       float* __restrict__ p) {
  int idx = blockIdx.x * 256 + threadIdx.x;     // 16384 = 16*1024
  int h = idx >> 10, i = idx & 1023;
  const float* kvp = kv + (size_t)(i * HEADS + h) * 128;
  const float* qp = q + h * 64;
  float s = 0.f;
#pragma unroll 8
  for (int d = 0; d < 64; ++d) s += san(kvp[2 * d]) * san(qp[d]);
  p[idx] = s;
}

// wv[n][k] = bf16(kv[k,h,d,1]),  n = h*64+d  (B^T layout for the V-GEMM)
__global__ void prep_wv(const float* __restrict__ kv, unsigned short* __restrict__ wv) {
  int idx = blockIdx.x * 256 + threadIdx.x;     // 1048576
  int n = idx >> 10, i = idx & 1023;
  int h = n >> 6, d = n & 63;
  wv[idx] = f2bf(san(kv[(size_t)(i * HEADS + h) * 128 + 2 * d + 1]));
}

__global__ void zero_h(float* __restrict__ h) {
  int idx = blockIdx.x * 256 + threadIdx.x;     // 131072 float4s = 2 MB
  *(float4*)&h[idx * 4] = float4{0.f, 0.f, 0.f, 0.f};
}

// st[b][h][t] = sum_i x[b,t,i] * p[h,i]  — pure fp32 (exp-sensitive path)
__global__ __launch_bounds__(256) void st_kernel(const float* __restrict__ x,
                                                 const float* __restrict__ p,
                                                 float* __restrict__ st) {
  __shared__ float xs[64][129];
  __shared__ float ps[16][129];
  int tid = threadIdx.x;
  int t0 = blockIdx.x * 64;
  int tt = tid & 63, hb = tid >> 6;     // 64 tokens x 4 head-groups
  float a0 = 0.f, a1 = 0.f, a2 = 0.f, a3 = 0.f;
  for (int kc = 0; kc < 1024; kc += 128) {
    __syncthreads();
#pragma unroll
    for (int vv = 0; vv < 8; ++vv) {    // stage x: 64 rows x 128 f32
      int idx = tid + vv * 256;         // 0..2047 float4s
      int row = idx >> 5, c4 = idx & 31;
      float4 val = *(const float4*)&x[(size_t)(t0 + row) * 1024 + kc + c4 * 4];
      float* dst = &xs[row][c4 * 4];
      dst[0] = san(val.x); dst[1] = san(val.y);
      dst[2] = san(val.z); dst[3] = san(val.w);
    }
#pragma unroll
    for (int vv = 0; vv < 2; ++vv) {    // stage p: 16 rows x 128 f32 (clean)
      int idx = tid + vv * 256;         // 0..511 float4s
      int row = idx >> 5, c4 = idx & 31;
      float4 val = *(const float4*)&p[(size_t)row * 1024 + kc + c4 * 4];
      float* dst = &ps[row][c4 * 4];
      dst[0] = val.x; dst[1] = val.y; dst[2] = val.z; dst[3] = val.w;
    }
    __syncthreads();
#pragma unroll 4
    for (int kk = 0; kk < 128; ++kk) {
      float xv = xs[tt][kk];
      a0 += xv * ps[hb * 4 + 0][kk];
      a1 += xv * ps[hb * 4 + 1][kk];
      a2 += xv * ps[hb * 4 + 2][kk];
      a3 += xv * ps[hb * 4 + 3][kk];
    }
  }
  int tg = t0 + tt, b = tg >> 11, tl = tg & 2047;
  st[(size_t)(b * HEADS + hb * 4 + 0) * TT + tl] = a0;
  st[(size_t)(b * HEADS + hb * 4 + 1) * TT + tl] = a1;
  st[(size_t)(b * HEADS + hb * 4 + 2) * TT + tl] = a2;
  st[(size_t)(b * HEADS + hb * 4 + 3) * TT + tl] = a3;
}

// V = x @ Wv  (A fp32 -> bf16 in staging; B bf16), v[b,h,t,d] stored bf16
__global__ __launch_bounds__(256) void vgemm(const float* __restrict__ A,
                                             const unsigned short* __restrict__ Bt,
                                             unsigned short* __restrict__ V) {
  __shared__ unsigned short As[128 * 40];   // stride 40 breaks bank conflicts
  __shared__ unsigned short Bs[128 * 40];
  int tid = threadIdx.x;
  int wave = tid >> 6, lane = tid & 63;
  int m0 = blockIdx.y * 128, n0 = blockIdx.x * 128;
  int wr = wave >> 1, wc = wave & 1;
  int lx = lane & 15, lq = lane >> 4;
  f32x4 acc[4][4] = {};
  for (int kt = 0; kt < 1024; kt += 32) {
    __syncthreads();
#pragma unroll
    for (int vv = 0; vv < 4; ++vv) {      // A: 128 rows x 32 f32 -> bf16
      int c = tid + vv * 256;             // 0..1023 float4s
      int r = c >> 3, seg = c & 7;
      float4 a = *(const float4*)&A[(size_t)(m0 + r) * 1024 + kt + seg * 4];
      *(uint2*)&As[r * 40 + seg * 4] =
          uint2{pk2(san(a.x), san(a.y)), pk2(san(a.z), san(a.w))};
    }
#pragma unroll
    for (int vv = 0; vv < 2; ++vv) {      // B: 128 rows x 32 bf16 (clean)
      int c = tid + vv * 256;             // 0..511
      int r = c >> 2, ks = (c & 3) * 8;
      short8 bv = *(const short8*)&Bt[(size_t)(n0 + r) * 1024 + kt + ks];
      *(short8*)&Bs[r * 40 + ks] = bv;
    }
    __syncthreads();
    short8 af[4], bfr[4];
#pragma unroll
    for (int i = 0; i < 4; ++i)
      af[i] = *(const short8*)&As[(wr * 64 + i * 16 + lx) * 40 + lq * 8];
#pragma unroll
    for (int j = 0; j < 4; ++j)
      bfr[j] = *(const short8*)&Bs[(wc * 64 + j * 16 + lx) * 40 + lq * 8];
#pragma unroll
    for (int i = 0; i < 4; ++i)
#pragma unroll
      for (int j = 0; j < 4; ++j)
        acc[i][j] = __builtin_amdgcn_mfma_f32_16x16x32_bf16(af[i], bfr[j], acc[i][j], 0, 0, 0);
  }
#pragma unroll
  for (int i = 0; i < 4; ++i)
#pragma unroll
    for (int j = 0; j < 4; ++j)
#pragma unroll
      for (int r = 0; r < 4; ++r) {
        int m = m0 + wr * 64 + i * 16 + lq * 4 + r;   // row = (lane>>4)*4+reg
        int n = n0 + wc * 64 + j * 16 + lx;           // col = lane&15
        int b = m >> 11, tl = m & 2047, h = n >> 6, d = n & 63;
        V[((size_t)(b * HEADS + h) << 17) + (tl << 6) + d] = f2bf(acc[i][j][r]);
      }
}

// per (b,h): max-shifted weighted prefix sums, SUBTRACTION-FREE denominators
// (uc built from additions of positives only -> uc >= e0 > 0, no cancellation);
// atomicAdd (W_t/U_t)/16 into h[tok][d]
__global__ __launch_bounds__(1024) void scan_kernel(const float* __restrict__ st,
                                                    const unsigned short* __restrict__ v,
                                                    float* __restrict__ hsum) {
  __shared__ float e[2048];
  __shared__ float uc[2048];
  __shared__ float psum[1024];
  __shared__ float cw[16][64];
  __shared__ float red[17];
  int tid = threadIdx.x;
  int wave = tid >> 6, lane = tid & 63;
  int bh = blockIdx.x;
  int b = bh >> 4;
  const float* stp = st + (size_t)bh * TT;
  const unsigned short* vp = v + ((size_t)bh << 17);
  float2 sv = *(const float2*)&stp[2 * tid];
  float m = fmaxf(sv.x, sv.y);
#pragma unroll
  for (int off = 32; off; off >>= 1) m = fmaxf(m, __shfl_down(m, off));
  if (lane == 0) red[wave] = m;
  __syncthreads();
  if (tid == 0) {
    float mm = red[0];
    for (int w = 1; w < 16; ++w) mm = fmaxf(mm, red[w]);
    red[16] = mm;
  }
  __syncthreads();
  float M = red[16];
  float e0 = __expf(sv.x - M), e1 = __expf(sv.y - M);
  e[2 * tid] = e0; e[2 * tid + 1] = e1;
  psum[tid] = e0 + e1;
  __syncthreads();
  for (int off = 1; off < 1024; off <<= 1) {   // Hillis-Steele, additions only
    float add = (tid >= off) ? psum[tid - off] : 0.f;
    __syncthreads();
    psum[tid] += add;
    __syncthreads();
  }
  float Pprev = (tid > 0) ? psum[tid - 1] : 0.f;  // exclusive via shifted read
  uc[2 * tid] = fmaxf(Pprev + e0, 1e-30f);        // additions only: uc > 0
  uc[2 * tid + 1] = fmaxf(Pprev + e0 + e1, 1e-30f);
  __syncthreads();
  int t0 = wave * 128;                         // chunk numerator sums
  float wsum = 0.f;
#pragma unroll 4
  for (int j = 0; j < 128; ++j)
    wsum += e[t0 + j] * b2f(vp[(size_t)(t0 + j) * 64 + lane]);
  cw[wave][lane] = wsum;
  __syncthreads();
  if (wave == 0) {                             // exclusive prefix over chunks
    float run = 0.f;
#pragma unroll
    for (int w = 0; w < 16; ++w) { float tmp = cw[w][lane]; cw[w][lane] = run; run += tmp; }
  }
  __syncthreads();
  float runW = cw[wave][lane];
#pragma unroll 2
  for (int j = 0; j < 128; ++j) {
    int t = t0 + j;
    runW += e[t] * b2f(vp[(size_t)t * 64 + lane]);
    atomicAdd(&hsum[(size_t)(b * TT + t) * 64 + lane], (runW / uc[t]) * 0.0625f);
  }
}

// out = h @ out_w^T + out_b  (h,ow fp32 -> bf16 staging; fp32 out, bias fused)
__global__ __launch_bounds__(256) void fgemm(const float* __restrict__ Ah,
                                             const float* __restrict__ Bw,
                                             const float* __restrict__ bias,
                                             float* __restrict__ C) {
  __shared__ unsigned short As[128 * 40];
  __shared__ unsigned short Bs[128 * 40];
  int tid = threadIdx.x;
  int wave = tid >> 6, lane = tid & 63;
  int m0 = blockIdx.y * 128, n0 = blockIdx.x * 128;
  int wr = wave >> 1, wc = wave & 1;
  int lx = lane & 15, lq = lane >> 4;
  f32x4 acc[4][4] = {};
  for (int kt = 0; kt < 64; kt += 32) {
    __syncthreads();
#pragma unroll
    for (int vv = 0; vv < 4; ++vv) {      // 0..1023: first 512 A, next 512 B
      int c = tid + vv * 256;
      int r = (c & 511) >> 2, seg = c & 3;
      if (c < 512) {
        float4 a = *(const float4*)&Ah[(size_t)(m0 + r) * 64 + kt + seg * 8];
        float4 a2 = *(const float4*)&Ah[(size_t)(m0 + r) * 64 + kt + seg * 8 + 4];
        *(uint4*)&As[r * 40 + seg * 8] =
            uint4{pk2(a.x, a.y), pk2(a.z, a.w), pk2(a2.x, a2.y), pk2(a2.z, a2.w)};
      } else {
        float4 bq = *(const float4*)&Bw[(size_t)(n0 + r) * 64 + kt + seg * 8];
        float4 b2 = *(const float4*)&Bw[(size_t)(n0 + r) * 64 + kt + seg * 8 + 4];
        *(uint4*)&Bs[r * 40 + seg * 8] =
            uint4{pk2(san(bq.x), san(bq.y)), pk2(san(bq.z), san(bq.w)),
                  pk2(san(b2.x), san(b2.y)), pk2(san(b2.z), san(b2.w))};
      }
    }
    __syncthreads();
    short8 af[4], bfr[4];
#pragma unroll
    for (int i = 0; i < 4; ++i)
      af[i] = *(const short8*)&As[(wr * 64 + i * 16 + lx) * 40 + lq * 8];
#pragma unroll
    for (int j = 0; j < 4; ++j)
      bfr[j] = *(const short8*)&Bs[(wc * 64 + j * 16 + lx) * 40 + lq * 8];
#pragma unroll
    for (int i = 0; i < 4; ++i)
#pragma unroll
      for (int j = 0; j < 4; ++j)
        acc[i][j] = __builtin_amdgcn_mfma_f32_16x16x32_bf16(af[i], bfr[j], acc[i][j], 0, 0, 0);
  }
#pragma unroll
  for (int i = 0; i < 4; ++i)
#pragma unroll
    for (int j = 0; j < 4; ++j)
#pragma unroll
      for (int r = 0; r < 4; ++r) {
        int m = m0 + wr * 64 + i * 16 + lq * 4 + r;
        int n = n0 + wc * 64 + j * 16 + lx;
        C[(size_t)m * 1024 + n] = acc[i][j][r] + san(bias[n]);
      }
}

extern "C" void kernel_launch(void* const* d_in, const int* in_sizes, int n_in,
                              void* d_out, int out_size, void* d_ws, size_t ws_size,
                              hipStream_t stream) {
  (void)in_sizes; (void)n_in; (void)out_size; (void)ws_size;
  const float* x  = (const float*)d_in[0];  // (4,2048,1024) f32
  const float* kv = (const float*)d_in[1];  // (1024,16,64,2) f32
  const float* q  = (const float*)d_in[2];  // (16,64) f32
  const float* ow = (const float*)d_in[3];  // (1024,64) f32
  const float* ob = (const float*)d_in[4];  // (1024,) f32
  char* ws = (char*)d_ws;
  unsigned short* wv = (unsigned short*)(ws + 0);   // 2 MB   [n=1024][k=1024] bf16
  float* p  = (float*)(ws + 2097152);               // 64 KB  [16][1024]
  float* st = (float*)(ws + 2162688);               // 512 KB [64 bh][2048]
  unsigned short* v = (unsigned short*)(ws + 2686976); // 16 MB [64 bh][2048][64] bf16
  float* h  = (float*)(ws + 19464192);              // 2 MB   [8192][64]
  float* out = (float*)d_out;

  hipLaunchKernelGGL(prep_p,      dim3(64),    dim3(256),  0, stream, kv, q, p);
  hipLaunchKernelGGL(prep_wv,     dim3(4096),  dim3(256),  0, stream, kv, wv);
  hipLaunchKernelGGL(zero_h,      dim3(512),   dim3(256),  0, stream, h);
  hipLaunchKernelGGL(st_kernel,   dim3(128),   dim3(256),  0, stream, x, p, st);
  hipLaunchKernelGGL(vgemm,       dim3(8, 64), dim3(256),  0, stream, x, wv, v);
  hipLaunchKernelGGL(scan_kernel, dim3(64),    dim3(1024), 0, stream, st, v, h);
  hipLaunchKernelGGL(fgemm,       dim3(8, 64), dim3(256),  0, stream, h, ow, ob, out);
}

// Round 5
// 251.848 us; speedup vs baseline: 1.0963x; 1.0963x over previous
//
#include <hip/hip_runtime.h>
#include <stdint.h>

typedef __attribute__((ext_vector_type(4))) float f32x4;
typedef __attribute__((ext_vector_type(8))) short short8;

#define HEADS 16
#define TT 2048

__device__ __forceinline__ float b2f(unsigned short u) {
  return __builtin_bit_cast(float, (uint32_t)u << 16);
}
__device__ __forceinline__ unsigned short f2bf(float f) {
  uint32_t u = __builtin_bit_cast(uint32_t, f);
  u += 0x7fffu + ((u >> 16) & 1u);
  return (unsigned short)(u >> 16);
}
__device__ __forceinline__ uint32_t pk2(float a, float b) {
  return (uint32_t)f2bf(a) | ((uint32_t)f2bf(b) << 16);
}

// x (fp32, 8.4M elems) -> xb (bf16), coalesced stream; 8 elems/thread
__global__ void xcast(const float* __restrict__ x, unsigned short* __restrict__ xb) {
  int idx = blockIdx.x * 256 + threadIdx.x;       // 1048576
  const float* src = x + (size_t)idx * 8;
  float4 a = *(const float4*)src;
  float4 b = *(const float4*)(src + 4);
  *(uint4*)(xb + (size_t)idx * 8) =
      uint4{pk2(a.x, a.y), pk2(a.z, a.w), pk2(b.x, b.y), pk2(b.z, b.w)};
}

// p[h][i] = sum_d Wk[i,h,d] * q[h,d]   (fold q into kv K-half; fp32)
__global__ void prep_p(const float* __restrict__ kv, const float* __restrict__ q,
                       float* __restrict__ p) {
  int idx = blockIdx.x * 256 + threadIdx.x;       // 16384 = 16*1024
  int h = idx >> 10, i = idx & 1023;
  const float* kvp = kv + (size_t)i * 2048 + (size_t)h * 128;  // K half stride 2
  const float* qp = q + h * 64;
  float s = 0.f;
#pragma unroll 8
  for (int d = 0; d < 64; ++d) s += kvp[2 * d] * qp[d];
  p[idx] = s;
}

// wv[hd][i] = bf16(kv[i*2048 + 2*hd + 1]) — LDS-tiled transpose, both sides coalesced
__global__ __launch_bounds__(256) void prep_wv(const float* __restrict__ kv,
                                               unsigned short* __restrict__ wv) {
  __shared__ unsigned short tile[64][66];
  int hd0 = blockIdx.x * 64, i0 = blockIdx.y * 64;
  int tid = threadIdx.x;
  int jj = tid & 63, r4 = tid >> 6;
#pragma unroll
  for (int s = 0; s < 16; ++s) {                  // read: lanes sweep hd (stride-2 f32)
    int ii = s * 4 + r4;
    tile[ii][jj] = f2bf(kv[(size_t)(i0 + ii) * 2048 + 2 * (hd0 + jj) + 1]);
  }
  __syncthreads();
#pragma unroll
  for (int s = 0; s < 16; ++s) {                  // write: lanes sweep i (coalesced)
    int jj2 = s * 4 + r4, ii2 = tid & 63;
    wv[(size_t)(hd0 + jj2) * 1024 + i0 + ii2] = tile[ii2][jj2];
  }
}

__global__ void zero_h(float* __restrict__ h) {
  int idx = blockIdx.x * 256 + threadIdx.x;       // 131072 float4s = 2 MB
  *(float4*)&h[idx * 4] = float4{0.f, 0.f, 0.f, 0.f};
}

// st[b][h][t] = sum_i x[b,t,i] * p[h,i]  — pure fp32 (exp-sensitive path)
__global__ __launch_bounds__(256) void st_kernel(const float* __restrict__ x,
                                                 const float* __restrict__ p,
                                                 float* __restrict__ st) {
  __shared__ float xs[64][129];
  __shared__ float ps[16][129];
  int tid = threadIdx.x;
  int t0 = blockIdx.x * 64;
  int tt = tid & 63, hb = tid >> 6;               // 64 tokens x 4 head-groups
  float a0 = 0.f, a1 = 0.f, a2 = 0.f, a3 = 0.f;
  for (int kc = 0; kc < 1024; kc += 128) {
    __syncthreads();
#pragma unroll
    for (int vv = 0; vv < 8; ++vv) {              // stage x: 64 rows x 128 f32
      int idx = tid + vv * 256;
      int row = idx >> 5, c4 = idx & 31;
      float4 val = *(const float4*)&x[(size_t)(t0 + row) * 1024 + kc + c4 * 4];
      float* dst = &xs[row][c4 * 4];
      dst[0] = val.x; dst[1] = val.y; dst[2] = val.z; dst[3] = val.w;
    }
#pragma unroll
    for (int vv = 0; vv < 2; ++vv) {              // stage p: 16 rows x 128 f32
      int idx = tid + vv * 256;
      int row = idx >> 5, c4 = idx & 31;
      float4 val = *(const float4*)&p[(size_t)row * 1024 + kc + c4 * 4];
      float* dst = &ps[row][c4 * 4];
      dst[0] = val.x; dst[1] = val.y; dst[2] = val.z; dst[3] = val.w;
    }
    __syncthreads();
#pragma unroll 4
    for (int kk = 0; kk < 128; ++kk) {
      float xv = xs[tt][kk];
      a0 += xv * ps[hb * 4 + 0][kk];
      a1 += xv * ps[hb * 4 + 1][kk];
      a2 += xv * ps[hb * 4 + 2][kk];
      a3 += xv * ps[hb * 4 + 3][kk];
    }
  }
  int tg = t0 + tt, b = tg >> 11, tl = tg & 2047;
  st[(size_t)(b * HEADS + hb * 4 + 0) * TT + tl] = a0;
  st[(size_t)(b * HEADS + hb * 4 + 1) * TT + tl] = a1;
  st[(size_t)(b * HEADS + hb * 4 + 2) * TT + tl] = a2;
  st[(size_t)(b * HEADS + hb * 4 + 3) * TT + tl] = a3;
}

// V = xb @ Wv   (both bf16, MFMA 128x128 tile), v[b,h,t,d] stored bf16
__global__ __launch_bounds__(256) void vgemm(const unsigned short* __restrict__ A,
                                             const unsigned short* __restrict__ Bt,
                                             unsigned short* __restrict__ V) {
  __shared__ unsigned short As[128 * 40];         // stride 40 breaks bank conflicts
  __shared__ unsigned short Bs[128 * 40];
  int tid = threadIdx.x;
  int wave = tid >> 6, lane = tid & 63;
  int m0 = blockIdx.y * 128, n0 = blockIdx.x * 128;
  int wr = wave >> 1, wc = wave & 1;
  int lx = lane & 15, lq = lane >> 4;
  f32x4 acc[4][4] = {};
  for (int kt = 0; kt < 1024; kt += 32) {
    __syncthreads();
#pragma unroll
    for (int vv = 0; vv < 2; ++vv) {
      int c = tid + vv * 256;                     // 512 chunks of 8 bf16
      int r = c >> 2, ks = (c & 3) * 8;
      short8 av = *(const short8*)&A[(size_t)(m0 + r) * 1024 + kt + ks];
      *(short8*)&As[r * 40 + ks] = av;
      short8 bv = *(const short8*)&Bt[(size_t)(n0 + r) * 1024 + kt + ks];
      *(short8*)&Bs[r * 40 + ks] = bv;
    }
    __syncthreads();
    short8 af[4], bfr[4];
#pragma unroll
    for (int i = 0; i < 4; ++i)
      af[i] = *(const short8*)&As[(wr * 64 + i * 16 + lx) * 40 + lq * 8];
#pragma unroll
    for (int j = 0; j < 4; ++j)
      bfr[j] = *(const short8*)&Bs[(wc * 64 + j * 16 + lx) * 40 + lq * 8];
#pragma unroll
    for (int i = 0; i < 4; ++i)
#pragma unroll
      for (int j = 0; j < 4; ++j)
        acc[i][j] = __builtin_amdgcn_mfma_f32_16x16x32_bf16(af[i], bfr[j], acc[i][j], 0, 0, 0);
  }
#pragma unroll
  for (int i = 0; i < 4; ++i)
#pragma unroll
    for (int j = 0; j < 4; ++j)
#pragma unroll
      for (int r = 0; r < 4; ++r) {
        int m = m0 + wr * 64 + i * 16 + lq * 4 + r;   // row = (lane>>4)*4+reg
        int n = n0 + wc * 64 + j * 16 + lx;           // col = lane&15
        int b = m >> 11, tl = m & 2047, h = n >> 6, d = n & 63;
        V[((size_t)(b * HEADS + h) << 17) + (tl << 6) + d] = f2bf(acc[i][j][r]);
      }
}

// ---- 3-phase chunked scan: chunk = 64 tokens, 32 chunks per (b,h) ----
// Phase 1: per-chunk max, exp-sum, weighted v-sum (relative to chunk max)
__global__ __launch_bounds__(64) void scan1(const float* __restrict__ st,
                                            const unsigned short* __restrict__ v,
                                            float* __restrict__ cmax,
                                            float* __restrict__ csum,
                                            float* __restrict__ cw) {
  int blk = blockIdx.x;                           // bh*32 + c
  int bh = blk >> 5, c = blk & 31;
  int lane = threadIdx.x;
  int t0 = c * 64;
  const float* stp = st + (size_t)bh * TT + t0;
  const unsigned short* vp = v + ((size_t)bh << 17) + ((size_t)t0 << 6);
  float stv = stp[lane];
  float Mc = stv;
#pragma unroll
  for (int off = 32; off; off >>= 1) Mc = fmaxf(Mc, __shfl_xor(Mc, off));
  float el = __expf(stv - Mc);
  float S = el;
#pragma unroll
  for (int off = 32; off; off >>= 1) S += __shfl_xor(S, off);
  float W = 0.f;
#pragma unroll 8
  for (int j = 0; j < 64; ++j)
    W += __shfl(el, j) * b2f(vp[j * 64 + lane]);
  if (lane == 0) { cmax[blk] = Mc; csum[blk] = S; }
  cw[(size_t)blk * 64 + lane] = W;
}

// Phase 2: global max per bh, rescale chunks, exclusive prefix over chunks
__global__ __launch_bounds__(64) void scan2(const float* __restrict__ cmax,
                                            const float* __restrict__ csum,
                                            const float* __restrict__ cw,
                                            float* __restrict__ Mg,
                                            float* __restrict__ E0,
                                            float* __restrict__ W0) {
  int bh = blockIdx.x, lane = threadIdx.x;
  float cm = (lane < 32) ? cmax[bh * 32 + lane] : -1e30f;
  float M = cm;
#pragma unroll
  for (int off = 32; off; off >>= 1) M = fmaxf(M, __shfl_xor(M, off));
  float cs = (lane < 32) ? csum[bh * 32 + lane] : 0.f;
  if (lane == 0) Mg[bh] = M;
  float runS = 0.f, runW = 0.f;
#pragma unroll
  for (int c = 0; c < 32; ++c) {
    float f = __expf(__shfl(cm, c) - M);
    float Sc = __shfl(cs, c) * f;
    if (lane == 0) E0[bh * 32 + c] = runS;
    runS += Sc;
    size_t idx = (size_t)(bh * 32 + c) * 64 + lane;
    W0[idx] = runW;
    runW += cw[idx] * f;
  }
}

// Phase 3: replay chunk with offsets; atomicAdd (W_t/U_t)/16 into h[tok][d]
__global__ __launch_bounds__(64) void scan3(const float* __restrict__ st,
                                            const unsigned short* __restrict__ v,
                                            const float* __restrict__ Mg,
                                            const float* __restrict__ E0,
                                            const float* __restrict__ W0,
                                            float* __restrict__ h) {
  int blk = blockIdx.x;
  int bh = blk >> 5, c = blk & 31;
  int lane = threadIdx.x;
  int b = bh >> 4;
  int t0 = c * 64;
  const float* stp = st + (size_t)bh * TT + t0;
  const unsigned short* vp = v + ((size_t)bh << 17) + ((size_t)t0 << 6);
  float M = Mg[bh];
  float runU = E0[blk];
  float runW = W0[(size_t)blk * 64 + lane];
  float el = __expf(stp[lane] - M);
  float* hp = h + ((size_t)(b * TT + t0) << 6) + lane;
#pragma unroll 8
  for (int j = 0; j < 64; ++j) {
    float ej = __shfl(el, j);
    runU += ej;                                   // inclusive, additions only
    runW += ej * b2f(vp[j * 64 + lane]);
    atomicAdd(&hp[j * 64], (runW / fmaxf(runU, 1e-30f)) * 0.0625f);
  }
}

// out = h @ out_w^T + out_b  (h,ow fp32 -> bf16 staging; fp32 out, bias fused)
__global__ __launch_bounds__(256) void fgemm(const float* __restrict__ Ah,
                                             const float* __restrict__ Bw,
                                             const float* __restrict__ bias,
                                             float* __restrict__ C) {
  __shared__ unsigned short As[128 * 40];
  __shared__ unsigned short Bs[128 * 40];
  int tid = threadIdx.x;
  int wave = tid >> 6, lane = tid & 63;
  int m0 = blockIdx.y * 128, n0 = blockIdx.x * 128;
  int wr = wave >> 1, wc = wave & 1;
  int lx = lane & 15, lq = lane >> 4;
  f32x4 acc[4][4] = {};
  for (int kt = 0; kt < 64; kt += 32) {
    __syncthreads();
#pragma unroll
    for (int vv = 0; vv < 4; ++vv) {              // 0..1023: first 512 A, next 512 B
      int c = tid + vv * 256;
      int r = (c & 511) >> 2, seg = c & 3;
      if (c < 512) {
        float4 a = *(const float4*)&Ah[(size_t)(m0 + r) * 64 + kt + seg * 8];
        float4 a2 = *(const float4*)&Ah[(size_t)(m0 + r) * 64 + kt + seg * 8 + 4];
        *(uint4*)&As[r * 40 + seg * 8] =
            uint4{pk2(a.x, a.y), pk2(a.z, a.w), pk2(a2.x, a2.y), pk2(a2.z, a2.w)};
      } else {
        float4 bq = *(const float4*)&Bw[(size_t)(n0 + r) * 64 + kt + seg * 8];
        float4 b2 = *(const float4*)&Bw[(size_t)(n0 + r) * 64 + kt + seg * 8 + 4];
        *(uint4*)&Bs[r * 40 + seg * 8] =
            uint4{pk2(bq.x, bq.y), pk2(bq.z, bq.w), pk2(b2.x, b2.y), pk2(b2.z, b2.w)};
      }
    }
    __syncthreads();
    short8 af[4], bfr[4];
#pragma unroll
    for (int i = 0; i < 4; ++i)
      af[i] = *(const short8*)&As[(wr * 64 + i * 16 + lx) * 40 + lq * 8];
#pragma unroll
    for (int j = 0; j < 4; ++j)
      bfr[j] = *(const short8*)&Bs[(wc * 64 + j * 16 + lx) * 40 + lq * 8];
#pragma unroll
    for (int i = 0; i < 4; ++i)
#pragma unroll
      for (int j = 0; j < 4; ++j)
        acc[i][j] = __builtin_amdgcn_mfma_f32_16x16x32_bf16(af[i], bfr[j], acc[i][j], 0, 0, 0);
  }
#pragma unroll
  for (int i = 0; i < 4; ++i)
#pragma unroll
    for (int j = 0; j < 4; ++j)
#pragma unroll
      for (int r = 0; r < 4; ++r) {
        int m = m0 + wr * 64 + i * 16 + lq * 4 + r;
        int n = n0 + wc * 64 + j * 16 + lx;
        C[(size_t)m * 1024 + n] = acc[i][j][r] + bias[n];
      }
}

extern "C" void kernel_launch(void* const* d_in, const int* in_sizes, int n_in,
                              void* d_out, int out_size, void* d_ws, size_t ws_size,
                              hipStream_t stream) {
  (void)in_sizes; (void)n_in; (void)out_size; (void)ws_size;
  const float* x  = (const float*)d_in[0];  // (4,2048,1024) f32
  const float* kv = (const float*)d_in[1];  // (1024,16,64,2) f32
  const float* q  = (const float*)d_in[2];  // (16,64) f32
  const float* ow = (const float*)d_in[3];  // (1024,64) f32
  const float* ob = (const float*)d_in[4];  // (1024,) f32
  char* ws = (char*)d_ws;
  unsigned short* xb = (unsigned short*)(ws + 0);        // 16 MB [8192][1024] bf16
  unsigned short* wv = (unsigned short*)(ws + 16777216); // 2 MB  [1024][1024] bf16
  float* p    = (float*)(ws + 18874368);                 // 64 KB [16][1024]
  float* st   = (float*)(ws + 18939904);                 // 512 KB [64 bh][2048]
  unsigned short* v = (unsigned short*)(ws + 19464192);  // 16 MB [64][2048][64] bf16
  float* cmax = (float*)(ws + 36241408);                 // 8 KB  [64][32]
  float* csum = (float*)(ws + 36249600);                 // 8 KB
  float* cw   = (float*)(ws + 36257792);                 // 512 KB [64][32][64]
  float* Mg   = (float*)(ws + 36782080);                 // 256 B [64]
  float* E0   = (float*)(ws + 36782336);                 // 8 KB
  float* W0   = (float*)(ws + 36790528);                 // 512 KB
  float* h    = (float*)(ws + 37314816);                 // 2 MB  [8192][64]
  float* out  = (float*)d_out;

  hipLaunchKernelGGL(xcast,     dim3(4096),     dim3(256), 0, stream, x, xb);
  hipLaunchKernelGGL(prep_p,    dim3(64),       dim3(256), 0, stream, kv, q, p);
  hipLaunchKernelGGL(prep_wv,   dim3(16, 16),   dim3(256), 0, stream, kv, wv);
  hipLaunchKernelGGL(zero_h,    dim3(512),      dim3(256), 0, stream, h);
  hipLaunchKernelGGL(st_kernel, dim3(128),      dim3(256), 0, stream, x, p, st);
  hipLaunchKernelGGL(vgemm,     dim3(8, 64),    dim3(256), 0, stream, xb, wv, v);
  hipLaunchKernelGGL(scan1,     dim3(2048),     dim3(64),  0, stream, st, v, cmax, csum, cw);
  hipLaunchKernelGGL(scan2,     dim3(64),       dim3(64),  0, stream, cmax, csum, cw, Mg, E0, W0);
  hipLaunchKernelGGL(scan3,     dim3(2048),     dim3(64),  0, stream, st, v, Mg, E0, W0, h);
  hipLaunchKernelGGL(fgemm,     dim3(8, 64),    dim3(256), 0, stream, h, ow, ob, out);
}

// Round 6
// 230.508 us; speedup vs baseline: 1.1978x; 1.0926x over previous
//
#include <hip/hip_runtime.h>
#include <stdint.h>

typedef __attribute__((ext_vector_type(4))) float f32x4;
typedef __attribute__((ext_vector_type(8))) short short8;

#define HEADS 16
#define TT 2048

__device__ __forceinline__ float b2f(unsigned short u) {
  return __builtin_bit_cast(float, (uint32_t)u << 16);
}
__device__ __forceinline__ unsigned short f2bf(float f) {
  uint32_t u = __builtin_bit_cast(uint32_t, f);
  u += 0x7fffu + ((u >> 16) & 1u);
  return (unsigned short)(u >> 16);
}
__device__ __forceinline__ uint32_t pk2(float a, float b) {
  return (uint32_t)f2bf(a) | ((uint32_t)f2bf(b) << 16);
}

// p[h][i] = sum_d Wk[i,h,d] * q[h,d]   (fold q into kv K-half; fp32)
__global__ void prep_p(const float* __restrict__ kv, const float* __restrict__ q,
                       float* __restrict__ p) {
  int idx = blockIdx.x * 256 + threadIdx.x;       // 16384 = 16*1024
  int h = idx >> 10, i = idx & 1023;
  const float* kvp = kv + (size_t)i * 2048 + (size_t)h * 128;  // K half stride 2
  const float* qp = q + h * 64;
  float s = 0.f;
#pragma unroll 8
  for (int d = 0; d < 64; ++d) s += kvp[2 * d] * qp[d];
  p[idx] = s;
}

// wv[hd][i] = bf16(kv[i*2048 + 2*hd + 1]) — LDS-tiled transpose, both sides coalesced
__global__ __launch_bounds__(256) void prep_wv(const float* __restrict__ kv,
                                               unsigned short* __restrict__ wv) {
  __shared__ unsigned short tile[64][66];
  int hd0 = blockIdx.x * 64, i0 = blockIdx.y * 64;
  int tid = threadIdx.x;
  int jj = tid & 63, r4 = tid >> 6;
#pragma unroll
  for (int s = 0; s < 16; ++s) {                  // read: lanes sweep hd
    int ii = s * 4 + r4;
    tile[ii][jj] = f2bf(kv[(size_t)(i0 + ii) * 2048 + 2 * (hd0 + jj) + 1]);
  }
  __syncthreads();
#pragma unroll
  for (int s = 0; s < 16; ++s) {                  // write: lanes sweep i (coalesced)
    int jj2 = s * 4 + r4, ii2 = tid & 63;
    wv[(size_t)(hd0 + jj2) * 1024 + i0 + ii2] = tile[ii2][jj2];
  }
}

// st[b][h][t] = sum_i x[b,t,i]*p[h,i] (fp32) AND xb = bf16(x) — x read ONCE
__global__ __launch_bounds__(256) void stx_kernel(const float* __restrict__ x,
                                                  const float* __restrict__ p,
                                                  unsigned short* __restrict__ xb,
                                                  float* __restrict__ st) {
  __shared__ float xs[32][129];
  __shared__ float ps[16][129];
  int tid = threadIdx.x;
  int t0 = blockIdx.x * 32;
  int tt = tid & 31, hb = tid >> 5;               // 32 tokens x 8 head-pairs
  float a0 = 0.f, a1 = 0.f;
  for (int kc = 0; kc < 1024; kc += 128) {
    __syncthreads();
#pragma unroll
    for (int vv = 0; vv < 4; ++vv) {              // x: 32 rows x 128 f32
      int idx = tid + vv * 256;                   // 0..1023 float4s
      int row = idx >> 5, c4 = idx & 31;
      float4 val = *(const float4*)&x[(size_t)(t0 + row) * 1024 + kc + c4 * 4];
      float* dst = &xs[row][c4 * 4];
      dst[0] = val.x; dst[1] = val.y; dst[2] = val.z; dst[3] = val.w;
      *(uint2*)&xb[(size_t)(t0 + row) * 1024 + kc + c4 * 4] =
          uint2{pk2(val.x, val.y), pk2(val.z, val.w)};
    }
#pragma unroll
    for (int vv = 0; vv < 2; ++vv) {              // p: 16 rows x 128 f32
      int idx = tid + vv * 256;
      int row = idx >> 5, c4 = idx & 31;
      float4 val = *(const float4*)&p[(size_t)row * 1024 + kc + c4 * 4];
      float* dst = &ps[row][c4 * 4];
      dst[0] = val.x; dst[1] = val.y; dst[2] = val.z; dst[3] = val.w;
    }
    __syncthreads();
#pragma unroll 4
    for (int kk = 0; kk < 128; ++kk) {
      float xv = xs[tt][kk];
      a0 += xv * ps[hb * 2 + 0][kk];
      a1 += xv * ps[hb * 2 + 1][kk];
    }
  }
  int tg = t0 + tt, b = tg >> 11, tl = tg & 2047;
  st[(size_t)(b * HEADS + hb * 2 + 0) * TT + tl] = a0;
  st[(size_t)(b * HEADS + hb * 2 + 1) * TT + tl] = a1;
}

// V = xb @ Wv   (both bf16, MFMA 128x128 tile), v[b,h,t,d] stored bf16
__global__ __launch_bounds__(256) void vgemm(const unsigned short* __restrict__ A,
                                             const unsigned short* __restrict__ Bt,
                                             unsigned short* __restrict__ V) {
  __shared__ unsigned short As[128 * 40];
  __shared__ unsigned short Bs[128 * 40];
  int tid = threadIdx.x;
  int wave = tid >> 6, lane = tid & 63;
  int m0 = blockIdx.y * 128, n0 = blockIdx.x * 128;
  int wr = wave >> 1, wc = wave & 1;
  int lx = lane & 15, lq = lane >> 4;
  f32x4 acc[4][4] = {};
  for (int kt = 0; kt < 1024; kt += 32) {
    __syncthreads();
#pragma unroll
    for (int vv = 0; vv < 2; ++vv) {
      int c = tid + vv * 256;                     // 512 chunks of 8 bf16
      int r = c >> 2, ks = (c & 3) * 8;
      short8 av = *(const short8*)&A[(size_t)(m0 + r) * 1024 + kt + ks];
      *(short8*)&As[r * 40 + ks] = av;
      short8 bv = *(const short8*)&Bt[(size_t)(n0 + r) * 1024 + kt + ks];
      *(short8*)&Bs[r * 40 + ks] = bv;
    }
    __syncthreads();
    short8 af[4], bfr[4];
#pragma unroll
    for (int i = 0; i < 4; ++i)
      af[i] = *(const short8*)&As[(wr * 64 + i * 16 + lx) * 40 + lq * 8];
#pragma unroll
    for (int j = 0; j < 4; ++j)
      bfr[j] = *(const short8*)&Bs[(wc * 64 + j * 16 + lx) * 40 + lq * 8];
#pragma unroll
    for (int i = 0; i < 4; ++i)
#pragma unroll
      for (int j = 0; j < 4; ++j)
        acc[i][j] = __builtin_amdgcn_mfma_f32_16x16x32_bf16(af[i], bfr[j], acc[i][j], 0, 0, 0);
  }
#pragma unroll
  for (int i = 0; i < 4; ++i)
#pragma unroll
    for (int j = 0; j < 4; ++j)
#pragma unroll
      for (int r = 0; r < 4; ++r) {
        int m = m0 + wr * 64 + i * 16 + lq * 4 + r;
        int n = n0 + wc * 64 + j * 16 + lx;
        int b = m >> 11, tl = m & 2047, h = n >> 6, d = n & 63;
        V[((size_t)(b * HEADS + h) << 17) + (tl << 6) + d] = f2bf(acc[i][j][r]);
      }
}

// ---- 3-phase chunked scan: chunk = 32 tokens, 64 chunks per (b,h) ----
// Phase 1: per-chunk max, exp-sum, weighted v-sums (relative to chunk max)
__global__ __launch_bounds__(64) void scan1(const float* __restrict__ st,
                                            const unsigned short* __restrict__ v,
                                            float* __restrict__ cmax,
                                            float* __restrict__ csum,
                                            float* __restrict__ cw) {
  int blk = blockIdx.x;                           // bh*64 + c
  int bh = blk >> 6, c = blk & 63;
  int lane = threadIdx.x;
  int t0 = c * 32;
  const float* stp = st + (size_t)bh * TT + t0;
  const unsigned short* vp = v + ((size_t)bh << 17) + ((size_t)t0 << 6);
  float stv = (lane < 32) ? stp[lane] : -1e30f;
  float Mc = stv;
#pragma unroll
  for (int off = 32; off; off >>= 1) Mc = fmaxf(Mc, __shfl_xor(Mc, off));
  float el = (lane < 32) ? __expf(stv - Mc) : 0.f;
  float S = el;
#pragma unroll
  for (int off = 32; off; off >>= 1) S += __shfl_xor(S, off);
  float W = 0.f;
#pragma unroll 8
  for (int j = 0; j < 32; ++j)
    W += __shfl(el, j) * b2f(vp[j * 64 + lane]);
  if (lane == 0) { cmax[blk] = Mc; csum[blk] = S; }
  cw[(size_t)blk * 64 + lane] = W;
}

// Phase 2: global max per bh, rescale chunks, exclusive prefix over 64 chunks
__global__ __launch_bounds__(64) void scan2(const float* __restrict__ cmax,
                                            const float* __restrict__ csum,
                                            const float* __restrict__ cw,
                                            float* __restrict__ Mg,
                                            float* __restrict__ E0,
                                            float* __restrict__ W0) {
  int bh = blockIdx.x, lane = threadIdx.x;
  float cm = cmax[bh * 64 + lane];
  float M = cm;
#pragma unroll
  for (int off = 32; off; off >>= 1) M = fmaxf(M, __shfl_xor(M, off));
  float cs = csum[bh * 64 + lane];
  if (lane == 0) Mg[bh] = M;
  float runS = 0.f, runW = 0.f;
  float cwn = cw[(size_t)(bh * 64) * 64 + lane];  // prefetch chunk 0
  for (int c = 0; c < 64; ++c) {
    float cwv = cwn;
    if (c < 63) cwn = cw[(size_t)(bh * 64 + c + 1) * 64 + lane];
    float f = __expf(__shfl(cm, c) - M);
    if (lane == 0) E0[bh * 64 + c] = runS;
    runS += __shfl(cs, c) * f;
    W0[(size_t)(bh * 64 + c) * 64 + lane] = runW;
    runW += cwv * f;
  }
}

// Phase 3: one block per (chunk,b); wave = head; LDS-accumulate the head-mean,
// single coalesced write of h — NO global atomics.
__global__ __launch_bounds__(1024) void scan3(const float* __restrict__ st,
                                              const unsigned short* __restrict__ v,
                                              const float* __restrict__ Mg,
                                              const float* __restrict__ E0,
                                              const float* __restrict__ W0,
                                              float* __restrict__ h) {
  __shared__ float hacc[32][64];                  // 8 KB; bank: 2 lanes/bank (free)
  int tid = threadIdx.x;
  int wave = tid >> 6, lane = tid & 63;
  int c = blockIdx.x;                             // 0..63 chunk
  int b = blockIdx.y;                             // 0..3
  int bh = b * HEADS + wave;
  int t0 = c * 32;
  for (int i = tid; i < 2048; i += 1024) ((float*)hacc)[i] = 0.f;
  __syncthreads();
  const float* stp = st + (size_t)bh * TT + t0;
  const unsigned short* vp = v + ((size_t)bh << 17) + ((size_t)t0 << 6);
  float M = Mg[bh];
  float runU = E0[bh * 64 + c];
  float runW = W0[(size_t)(bh * 64 + c) * 64 + lane];
  float el = (lane < 32) ? __expf(stp[lane] - M) : 0.f;
#pragma unroll 8
  for (int j = 0; j < 32; ++j) {
    float ej = __shfl(el, j);
    runU += ej;                                   // additions only: runU > 0
    runW += ej * b2f(vp[j * 64 + lane]);
    atomicAdd(&hacc[j][lane], (runW / fmaxf(runU, 1e-30f)) * 0.0625f);
  }
  __syncthreads();
  for (int i = tid; i < 2048; i += 1024) {
    int j = i >> 6, d = i & 63;
    h[((size_t)(b * TT + t0 + j) << 6) + d] = hacc[j][d];
  }
}

// out = h @ out_w^T + out_b  (h,ow fp32 -> bf16 staging; fp32 out, bias fused)
__global__ __launch_bounds__(256) void fgemm(const float* __restrict__ Ah,
                                             const float* __restrict__ Bw,
                                             const float* __restrict__ bias,
                                             float* __restrict__ C) {
  __shared__ unsigned short As[128 * 40];
  __shared__ unsigned short Bs[128 * 40];
  int tid = threadIdx.x;
  int wave = tid >> 6, lane = tid & 63;
  int m0 = blockIdx.y * 128, n0 = blockIdx.x * 128;
  int wr = wave >> 1, wc = wave & 1;
  int lx = lane & 15, lq = lane >> 4;
  f32x4 acc[4][4] = {};
  for (int kt = 0; kt < 64; kt += 32) {
    __syncthreads();
#pragma unroll
    for (int vv = 0; vv < 4; ++vv) {              // 0..1023: first 512 A, next 512 B
      int c = tid + vv * 256;
      int r = (c & 511) >> 2, seg = c & 3;
      if (c < 512) {
        float4 a = *(const float4*)&Ah[(size_t)(m0 + r) * 64 + kt + seg * 8];
        float4 a2 = *(const float4*)&Ah[(size_t)(m0 + r) * 64 + kt + seg * 8 + 4];
        *(uint4*)&As[r * 40 + seg * 8] =
            uint4{pk2(a.x, a.y), pk2(a.z, a.w), pk2(a2.x, a2.y), pk2(a2.z, a2.w)};
      } else {
        float4 bq = *(const float4*)&Bw[(size_t)(n0 + r) * 64 + kt + seg * 8];
        float4 b2 = *(const float4*)&Bw[(size_t)(n0 + r) * 64 + kt + seg * 8 + 4];
        *(uint4*)&Bs[r * 40 + seg * 8] =
            uint4{pk2(bq.x, bq.y), pk2(bq.z, bq.w), pk2(b2.x, b2.y), pk2(b2.z, b2.w)};
      }
    }
    __syncthreads();
    short8 af[4], bfr[4];
#pragma unroll
    for (int i = 0; i < 4; ++i)
      af[i] = *(const short8*)&As[(wr * 64 + i * 16 + lx) * 40 + lq * 8];
#pragma unroll
    for (int j = 0; j < 4; ++j)
      bfr[j] = *(const short8*)&Bs[(wc * 64 + j * 16 + lx) * 40 + lq * 8];
#pragma unroll
    for (int i = 0; i < 4; ++i)
#pragma unroll
      for (int j = 0; j < 4; ++j)
        acc[i][j] = __builtin_amdgcn_mfma_f32_16x16x32_bf16(af[i], bfr[j], acc[i][j], 0, 0, 0);
  }
#pragma unroll
  for (int i = 0; i < 4; ++i)
#pragma unroll
    for (int j = 0; j < 4; ++j)
#pragma unroll
      for (int r = 0; r < 4; ++r) {
        int m = m0 + wr * 64 + i * 16 + lq * 4 + r;
        int n = n0 + wc * 64 + j * 16 + lx;
        C[(size_t)m * 1024 + n] = acc[i][j][r] + bias[n];
      }
}

extern "C" void kernel_launch(void* const* d_in, const int* in_sizes, int n_in,
                              void* d_out, int out_size, void* d_ws, size_t ws_size,
                              hipStream_t stream) {
  (void)in_sizes; (void)n_in; (void)out_size; (void)ws_size;
  const float* x  = (const float*)d_in[0];  // (4,2048,1024) f32
  const float* kv = (const float*)d_in[1];  // (1024,16,64,2) f32
  const float* q  = (const float*)d_in[2];  // (16,64) f32
  const float* ow = (const float*)d_in[3];  // (1024,64) f32
  const float* ob = (const float*)d_in[4];  // (1024,) f32
  char* ws = (char*)d_ws;
  unsigned short* xb = (unsigned short*)(ws + 0);        // 16 MB [8192][1024] bf16
  unsigned short* wv = (unsigned short*)(ws + 16777216); // 2 MB  [1024][1024] bf16
  float* p    = (float*)(ws + 18874368);                 // 64 KB [16][1024]
  float* st   = (float*)(ws + 18939904);                 // 512 KB [64 bh][2048]
  unsigned short* v = (unsigned short*)(ws + 19464192);  // 16 MB [64][2048][64] bf16
  float* cmax = (float*)(ws + 36241408);                 // 16 KB [64 bh][64 c]
  float* csum = (float*)(ws + 36257792);                 // 16 KB
  float* cw   = (float*)(ws + 36274176);                 // 1 MB  [64][64][64]
  float* Mg   = (float*)(ws + 37322752);                 // 256 B [64]
  float* E0   = (float*)(ws + 37323008);                 // 16 KB
  float* W0   = (float*)(ws + 37339392);                 // 1 MB
  float* h    = (float*)(ws + 38387968);                 // 2 MB  [8192][64]
  float* out  = (float*)d_out;

  hipLaunchKernelGGL(prep_p,     dim3(64),     dim3(256),  0, stream, kv, q, p);
  hipLaunchKernelGGL(prep_wv,    dim3(16, 16), dim3(256),  0, stream, kv, wv);
  hipLaunchKernelGGL(stx_kernel, dim3(256),    dim3(256),  0, stream, x, p, xb, st);
  hipLaunchKernelGGL(vgemm,      dim3(8, 64),  dim3(256),  0, stream, xb, wv, v);
  hipLaunchKernelGGL(scan1,      dim3(4096),   dim3(64),   0, stream, st, v, cmax, csum, cw);
  hipLaunchKernelGGL(scan2,      dim3(64),     dim3(64),   0, stream, cmax, csum, cw, Mg, E0, W0);
  hipLaunchKernelGGL(scan3,      dim3(64, 4),  dim3(1024), 0, stream, st, v, Mg, E0, W0, h);
  hipLaunchKernelGGL(fgemm,      dim3(8, 64),  dim3(256),  0, stream, h, ow, ob, out);
}

// Round 8
// 223.148 us; speedup vs baseline: 1.2373x; 1.0330x over previous
//
#include <hip/hip_runtime.h>
#include <stdint.h>

typedef __attribute__((ext_vector_type(4))) float f32x4;
typedef __attribute__((ext_vector_type(8))) short short8;

#define HEADS 16
#define TT 2048

__device__ __forceinline__ float b2f(unsigned short u) {
  return __builtin_bit_cast(float, (uint32_t)u << 16);
}
__device__ __forceinline__ unsigned short f2bf(float f) {
  uint32_t u = __builtin_bit_cast(uint32_t, f);
  u += 0x7fffu + ((u >> 16) & 1u);
  return (unsigned short)(u >> 16);
}
__device__ __forceinline__ uint32_t pk2(float a, float b) {
  return (uint32_t)f2bf(a) | ((uint32_t)f2bf(b) << 16);
}

// p[h][i] = sum_d Wk[i,h,d] * q[h,d]   (fold q into kv K-half; fp32)
__global__ void prep_p(const float* __restrict__ kv, const float* __restrict__ q,
                       float* __restrict__ p) {
  int idx = blockIdx.x * 256 + threadIdx.x;       // 16384 = 16*1024
  int h = idx >> 10, i = idx & 1023;
  const float* kvp = kv + (size_t)i * 2048 + (size_t)h * 128;
  const float* qp = q + h * 64;
  float s = 0.f;
#pragma unroll 8
  for (int d = 0; d < 64; ++d) s += kvp[2 * d] * qp[d];
  p[idx] = s;
}

// wv[hd][i] = bf16(kv[i*2048 + 2*hd + 1]) — LDS-tiled transpose
__global__ __launch_bounds__(256) void prep_wv(const float* __restrict__ kv,
                                               unsigned short* __restrict__ wv) {
  __shared__ unsigned short tile[64][66];
  int hd0 = blockIdx.x * 64, i0 = blockIdx.y * 64;
  int tid = threadIdx.x;
  int jj = tid & 63, r4 = tid >> 6;
#pragma unroll
  for (int s = 0; s < 16; ++s) {
    int ii = s * 4 + r4;
    tile[ii][jj] = f2bf(kv[(size_t)(i0 + ii) * 2048 + 2 * (hd0 + jj) + 1]);
  }
  __syncthreads();
#pragma unroll
  for (int s = 0; s < 16; ++s) {
    int jj2 = s * 4 + r4, ii2 = tid & 63;
    wv[(size_t)(hd0 + jj2) * 1024 + i0 + ii2] = tile[ii2][jj2];
  }
}

// st[b][h][t] = sum_i x[b,t,i]*p[h,i] (fp32) AND xb = bf16(x) — x read ONCE
__global__ __launch_bounds__(256) void stx_kernel(const float* __restrict__ x,
                                                  const float* __restrict__ p,
                                                  unsigned short* __restrict__ xb,
                                                  float* __restrict__ st) {
  __shared__ float xs[32][129];
  __shared__ float ps[16][129];
  int tid = threadIdx.x;
  int t0 = blockIdx.x * 32;
  int tt = tid & 31, hb = tid >> 5;               // 32 tokens x 8 head-pairs
  float a0 = 0.f, a1 = 0.f;
  for (int kc = 0; kc < 1024; kc += 128) {
    __syncthreads();
#pragma unroll
    for (int vv = 0; vv < 4; ++vv) {              // x: 32 rows x 128 f32
      int idx = tid + vv * 256;
      int row = idx >> 5, c4 = idx & 31;
      float4 val = *(const float4*)&x[(size_t)(t0 + row) * 1024 + kc + c4 * 4];
      float* dst = &xs[row][c4 * 4];
      dst[0] = val.x; dst[1] = val.y; dst[2] = val.z; dst[3] = val.w;
      *(uint2*)&xb[(size_t)(t0 + row) * 1024 + kc + c4 * 4] =
          uint2{pk2(val.x, val.y), pk2(val.z, val.w)};
    }
#pragma unroll
    for (int vv = 0; vv < 2; ++vv) {              // p: 16 rows x 128 f32
      int idx = tid + vv * 256;
      int row = idx >> 5, c4 = idx & 31;
      float4 val = *(const float4*)&p[(size_t)row * 1024 + kc + c4 * 4];
      float* dst = &ps[row][c4 * 4];
      dst[0] = val.x; dst[1] = val.y; dst[2] = val.z; dst[3] = val.w;
    }
    __syncthreads();
#pragma unroll 4
    for (int kk = 0; kk < 128; ++kk) {
      float xv = xs[tt][kk];
      a0 += xv * ps[hb * 2 + 0][kk];
      a1 += xv * ps[hb * 2 + 1][kk];
    }
  }
  int tg = t0 + tt, b = tg >> 11, tl = tg & 2047;
  st[(size_t)(b * HEADS + hb * 2 + 0) * TT + tl] = a0;
  st[(size_t)(b * HEADS + hb * 2 + 1) * TT + tl] = a1;
}

// V = xb @ Wv   (both bf16, MFMA 128x128 tile), v[b,h,t,d] stored bf16
__global__ __launch_bounds__(256) void vgemm(const unsigned short* __restrict__ A,
                                             const unsigned short* __restrict__ Bt,
                                             unsigned short* __restrict__ V) {
  __shared__ unsigned short As[128 * 40];
  __shared__ unsigned short Bs[128 * 40];
  int tid = threadIdx.x;
  int wave = tid >> 6, lane = tid & 63;
  int m0 = blockIdx.y * 128, n0 = blockIdx.x * 128;
  int wr = wave >> 1, wc = wave & 1;
  int lx = lane & 15, lq = lane >> 4;
  f32x4 acc[4][4] = {};
  for (int kt = 0; kt < 1024; kt += 32) {
    __syncthreads();
#pragma unroll
    for (int vv = 0; vv < 2; ++vv) {
      int c = tid + vv * 256;
      int r = c >> 2, ks = (c & 3) * 8;
      short8 av = *(const short8*)&A[(size_t)(m0 + r) * 1024 + kt + ks];
      *(short8*)&As[r * 40 + ks] = av;
      short8 bv = *(const short8*)&Bt[(size_t)(n0 + r) * 1024 + kt + ks];
      *(short8*)&Bs[r * 40 + ks] = bv;
    }
    __syncthreads();
    short8 af[4], bfr[4];
#pragma unroll
    for (int i = 0; i < 4; ++i)
      af[i] = *(const short8*)&As[(wr * 64 + i * 16 + lx) * 40 + lq * 8];
#pragma unroll
    for (int j = 0; j < 4; ++j)
      bfr[j] = *(const short8*)&Bs[(wc * 64 + j * 16 + lx) * 40 + lq * 8];
#pragma unroll
    for (int i = 0; i < 4; ++i)
#pragma unroll
      for (int j = 0; j < 4; ++j)
        acc[i][j] = __builtin_amdgcn_mfma_f32_16x16x32_bf16(af[i], bfr[j], acc[i][j], 0, 0, 0);
  }
#pragma unroll
  for (int i = 0; i < 4; ++i)
#pragma unroll
    for (int j = 0; j < 4; ++j)
#pragma unroll
      for (int r = 0; r < 4; ++r) {
        int m = m0 + wr * 64 + i * 16 + lq * 4 + r;
        int n = n0 + wc * 64 + j * 16 + lx;
        int b = m >> 11, tl = m & 2047, h = n >> 6, d = n & 63;
        V[((size_t)(b * HEADS + h) << 17) + (tl << 6) + d] = f2bf(acc[i][j][r]);
      }
}

// Phase 1: per-chunk (32 tok) max, exp-sum, weighted v-sums; loads hoisted
__global__ __launch_bounds__(64) void scan1(const float* __restrict__ st,
                                            const unsigned short* __restrict__ v,
                                            float* __restrict__ cmax,
                                            float* __restrict__ csum,
                                            float* __restrict__ cw) {
  int blk = blockIdx.x;                           // bh*64 + c
  int bh = blk >> 6, c = blk & 63;
  int lane = threadIdx.x;
  int t0 = c * 32;
  const float* stp = st + (size_t)bh * TT + t0;
  const unsigned short* vp = v + ((size_t)bh << 17) + ((size_t)t0 << 6);
  float vj[32];
#pragma unroll
  for (int j = 0; j < 32; ++j) vj[j] = b2f(vp[j * 64 + lane]);  // batched
  float stv = (lane < 32) ? stp[lane] : -1e30f;
  float Mc = stv;
#pragma unroll
  for (int off = 32; off; off >>= 1) Mc = fmaxf(Mc, __shfl_xor(Mc, off));
  float el = (lane < 32) ? __expf(stv - Mc) : 0.f;
  float S = el;
#pragma unroll
  for (int off = 32; off; off >>= 1) S += __shfl_xor(S, off);
  float W = 0.f;
#pragma unroll
  for (int j = 0; j < 32; ++j) W = fmaf(__shfl(el, j), vj[j], W);
  if (lane == 0) { cmax[blk] = Mc; csum[blk] = S; }
  cw[(size_t)blk * 64 + lane] = W;
}

// Phase 2: wave-parallel prefix over 64 chunks (lane = chunk). Exclusive via
// SHIFT of inclusive (subtraction-free — partial sums only involve chunks < c).
__global__ __launch_bounds__(1024) void scan2(const float* __restrict__ cmax,
                                              const float* __restrict__ csum,
                                              const float* __restrict__ cw,
                                              float* __restrict__ Mg,
                                              float* __restrict__ E0,
                                              float* __restrict__ W0) {
  int bh = blockIdx.x;
  int tid = threadIdx.x, wave = tid >> 6, lane = tid & 63;   // lane = chunk
  float cm = cmax[bh * 64 + lane];
  float M = cm;
#pragma unroll
  for (int off = 32; off; off >>= 1) M = fmaxf(M, __shfl_xor(M, off));
  float f = __expf(cm - M);
  if (wave == 0) {
    if (lane == 0) Mg[bh] = M;
    float incl = csum[bh * 64 + lane] * f;
#pragma unroll
    for (int off = 1; off < 64; off <<= 1) {
      float n = __shfl_up(incl, off);
      if (lane >= off) incl += n;
    }
    float excl = __shfl_up(incl, 1);              // shift, not subtract
    E0[bh * 64 + lane] = (lane == 0) ? 0.f : excl;
  }
#pragma unroll
  for (int dd = 0; dd < 4; ++dd) {
    int d = wave * 4 + dd;
    float incl = cw[((size_t)bh * 64 + lane) * 64 + d] * f;
#pragma unroll
    for (int off = 1; off < 64; off <<= 1) {
      float n = __shfl_up(incl, off);
      if (lane >= off) incl += n;
    }
    float excl = __shfl_up(incl, 1);              // shift, not subtract
    W0[((size_t)bh * 64 + lane) * 64 + d] = (lane == 0) ? 0.f : excl;
  }
}

// Phase 3: block per (chunk,b); wave = head. Loads hoisted, rcp, quotients in
// regs (static index), then LDS-atomic head-mean, one coalesced write.
__global__ __launch_bounds__(1024) void scan3(const float* __restrict__ st,
                                              const unsigned short* __restrict__ v,
                                              const float* __restrict__ Mg,
                                              const float* __restrict__ E0,
                                              const float* __restrict__ W0,
                                              float* __restrict__ h) {
  __shared__ float hacc[32][64];                  // 8 KB
  int tid = threadIdx.x;
  int wave = tid >> 6, lane = tid & 63;
  int c = blockIdx.x, b = blockIdx.y;
  int bh = b * HEADS + wave;
  int t0 = c * 32;
  for (int i = tid; i < 2048; i += 1024) ((float*)hacc)[i] = 0.f;
  const float* stp = st + (size_t)bh * TT + t0;
  const unsigned short* vp = v + ((size_t)bh << 17) + ((size_t)t0 << 6);
  float vj[32];
#pragma unroll
  for (int j = 0; j < 32; ++j) vj[j] = b2f(vp[j * 64 + lane]);  // one vmcnt batch
  float M = Mg[bh];
  float runU = E0[bh * 64 + c];
  float runW = W0[(size_t)(bh * 64 + c) * 64 + lane];
  float el = (lane < 32) ? __expf(stp[lane] - M) : 0.f;
  float qv[32];
#pragma unroll
  for (int j = 0; j < 32; ++j) {                  // pure-VALU serial chain
    float ej = __shfl(el, j);                     // const j -> v_readlane
    runU += ej;
    runW = fmaf(ej, vj[j], runW);
    qv[j] = runW * __builtin_amdgcn_rcpf(fmaxf(runU, 1e-30f)) * 0.0625f;
  }
  __syncthreads();
#pragma unroll
  for (int j = 0; j < 32; ++j)                    // static index: stays in regs
    atomicAdd(&hacc[j][lane], qv[j]);
  __syncthreads();
  for (int i = tid; i < 2048; i += 1024) {
    int j = i >> 6, d = i & 63;
    h[((size_t)(b * TT + t0 + j) << 6) + d] = hacc[j][d];
  }
}

// out = h @ out_w^T + out_b  (fp32 -> bf16 staging; fp32 out, bias fused)
__global__ __launch_bounds__(256) void fgemm(const float* __restrict__ Ah,
                                             const float* __restrict__ Bw,
                                             const float* __restrict__ bias,
                                             float* __restrict__ C) {
  __shared__ unsigned short As[128 * 40];
  __shared__ unsigned short Bs[128 * 40];
  int tid = threadIdx.x;
  int wave = tid >> 6, lane = tid & 63;
  int m0 = blockIdx.y * 128, n0 = blockIdx.x * 128;
  int wr = wave >> 1, wc = wave & 1;
  int lx = lane & 15, lq = lane >> 4;
  f32x4 acc[4][4] = {};
  for (int kt = 0; kt < 64; kt += 32) {
    __syncthreads();
#pragma unroll
    for (int vv = 0; vv < 4; ++vv) {
      int c = tid + vv * 256;
      int r = (c & 511) >> 2, seg = c & 3;
      if (c < 512) {
        float4 a = *(const float4*)&Ah[(size_t)(m0 + r) * 64 + kt + seg * 8];
        float4 a2 = *(const float4*)&Ah[(size_t)(m0 + r) * 64 + kt + seg * 8 + 4];
        *(uint4*)&As[r * 40 + seg * 8] =
            uint4{pk2(a.x, a.y), pk2(a.z, a.w), pk2(a2.x, a2.y), pk2(a2.z, a2.w)};
      } else {
        float4 bq = *(const float4*)&Bw[(size_t)(n0 + r) * 64 + kt + seg * 8];
        float4 b2 = *(const float4*)&Bw[(size_t)(n0 + r) * 64 + kt + seg * 8 + 4];
        *(uint4*)&Bs[r * 40 + seg * 8] =
            uint4{pk2(bq.x, bq.y), pk2(bq.z, bq.w), pk2(b2.x, b2.y), pk2(b2.z, b2.w)};
      }
    }
    __syncthreads();
    short8 af[4], bfr[4];
#pragma unroll
    for (int i = 0; i < 4; ++i)
      af[i] = *(const short8*)&As[(wr * 64 + i * 16 + lx) * 40 + lq * 8];
#pragma unroll
    for (int j = 0; j < 4; ++j)
      bfr[j] = *(const short8*)&Bs[(wc * 64 + j * 16 + lx) * 40 + lq * 8];
#pragma unroll
    for (int i = 0; i < 4; ++i)
#pragma unroll
      for (int j = 0; j < 4; ++j)
        acc[i][j] = __builtin_amdgcn_mfma_f32_16x16x32_bf16(af[i], bfr[j], acc[i][j], 0, 0, 0);
  }
#pragma unroll
  for (int i = 0; i < 4; ++i)
#pragma unroll
    for (int j = 0; j < 4; ++j)
#pragma unroll
      for (int r = 0; r < 4; ++r) {
        int m = m0 + wr * 64 + i * 16 + lq * 4 + r;
        int n = n0 + wc * 64 + j * 16 + lx;
        C[(size_t)m * 1024 + n] = acc[i][j][r] + bias[n];
      }
}

extern "C" void kernel_launch(void* const* d_in, const int* in_sizes, int n_in,
                              void* d_out, int out_size, void* d_ws, size_t ws_size,
                              hipStream_t stream) {
  (void)in_sizes; (void)n_in; (void)out_size; (void)ws_size;
  const float* x  = (const float*)d_in[0];
  const float* kv = (const float*)d_in[1];
  const float* q  = (const float*)d_in[2];
  const float* ow = (const float*)d_in[3];
  const float* ob = (const float*)d_in[4];
  char* ws = (char*)d_ws;
  unsigned short* xb = (unsigned short*)(ws + 0);        // 16 MB
  unsigned short* wv = (unsigned short*)(ws + 16777216); // 2 MB
  float* p    = (float*)(ws + 18874368);                 // 64 KB
  float* st   = (float*)(ws + 18939904);                 // 512 KB
  unsigned short* v = (unsigned short*)(ws + 19464192);  // 16 MB
  float* cmax = (float*)(ws + 36241408);                 // 16 KB
  float* csum = (float*)(ws + 36257792);                 // 16 KB
  float* cw   = (float*)(ws + 36274176);                 // 1 MB
  float* Mg   = (float*)(ws + 37322752);                 // 256 B
  float* E0   = (float*)(ws + 37323008);                 // 16 KB
  float* W0   = (float*)(ws + 37339392);                 // 1 MB
  float* h    = (float*)(ws + 38387968);                 // 2 MB
  float* out  = (float*)d_out;

  hipLaunchKernelGGL(prep_p,     dim3(64),     dim3(256),  0, stream, kv, q, p);
  hipLaunchKernelGGL(prep_wv,    dim3(16, 16), dim3(256),  0, stream, kv, wv);
  hipLaunchKernelGGL(stx_kernel, dim3(256),    dim3(256),  0, stream, x, p, xb, st);
  hipLaunchKernelGGL(vgemm,      dim3(8, 64),  dim3(256),  0, stream, xb, wv, v);
  hipLaunchKernelGGL(scan1,      dim3(4096),   dim3(64),   0, stream, st, v, cmax, csum, cw);
  hipLaunchKernelGGL(scan2,      dim3(64),     dim3(1024), 0, stream, cmax, csum, cw, Mg, E0, W0);
  hipLaunchKernelGGL(scan3,      dim3(64, 4),  dim3(1024), 0, stream, st, v, Mg, E0, W0, h);
  hipLaunchKernelGGL(fgemm,      dim3(8, 64),  dim3(256),  0, stream, h, ow, ob, out);
}